// Round 1
// baseline (149.250 us; speedup 1.0000x reference)
//
#include <hip/hip_runtime.h>

// Problem constants (match reference setup_inputs()).
#define NV     10000     // base mesh vertices (N)
#define MPTS   500000    // target points (M)
#define BATCH  128       // scalar fields (B)

#define BLOCK  256       // threads per block
#define T      16        // m-values per thread  -> 4096 m per block
#define BSPLIT 8         // grid.y: batch split  -> 16 b-rows per block
#define BPB    (BATCH / BSPLIT)

__global__ __launch_bounds__(BLOCK)
void bary_interp_kernel(const float* __restrict__ f,    // (B, N)
                        const int*   __restrict__ tri,  // (M, 3)
                        const float* __restrict__ w,    // (M, 3)
                        float*       __restrict__ out)  // (B, M)
{
    __shared__ float row[NV];   // 40 KB: one f-row staged per b-iteration

    const int m_base = blockIdx.x * (BLOCK * T);
    const int b0     = blockIdx.y * BPB;

    // Load this thread's indices/weights once (lane-contiguous m for coalescing).
    int   i0[T], i1[T], i2[T];
    float w0[T], w1[T], w2[T];
#pragma unroll
    for (int t = 0; t < T; ++t) {
        const int m = m_base + t * BLOCK + (int)threadIdx.x;
        if (m < MPTS) {
            i0[t] = tri[3 * m + 0];
            i1[t] = tri[3 * m + 1];
            i2[t] = tri[3 * m + 2];
            w0[t] = w[3 * m + 0];
            w1[t] = w[3 * m + 1];
            w2[t] = w[3 * m + 2];
        } else {
            i0[t] = i1[t] = i2[t] = 0;
            w0[t] = w1[t] = w2[t] = 0.0f;
        }
    }

    for (int bb = 0; bb < BPB; ++bb) {
        const int b = b0 + bb;

        if (bb) __syncthreads();   // previous compute done before overwriting row

        // Stage f-row b into LDS with float4 loads (NV % 4 == 0).
        {
            const float4* src = reinterpret_cast<const float4*>(f + (size_t)b * NV);
            float4*       dst = reinterpret_cast<float4*>(row);
            for (int i = (int)threadIdx.x; i < NV / 4; i += BLOCK)
                dst[i] = src[i];
        }
        __syncthreads();

        float* o = out + (size_t)b * MPTS;
#pragma unroll
        for (int t = 0; t < T; ++t) {
            const int m = m_base + t * BLOCK + (int)threadIdx.x;
            if (m < MPTS) {
                o[m] = row[i0[t]] * w0[t]
                     + row[i1[t]] * w1[t]
                     + row[i2[t]] * w2[t];
            }
        }
    }
}

extern "C" void kernel_launch(void* const* d_in, const int* in_sizes, int n_in,
                              void* d_out, int out_size, void* d_ws, size_t ws_size,
                              hipStream_t stream) {
    const float* f   = (const float*)d_in[0];   // (B, N)  float32
    const int*   tri = (const int*)  d_in[1];   // (M, 3)  int32
    const float* w   = (const float*)d_in[2];   // (M, 3)  float32
    float*       out = (float*)d_out;           // (B, M)  float32

    const int mblocks = (MPTS + BLOCK * T - 1) / (BLOCK * T);  // 123
    dim3 grid(mblocks, BSPLIT);
    bary_interp_kernel<<<grid, BLOCK, 0, stream>>>(f, tri, w, out);
}

// Round 2
// 110.534 us; speedup vs baseline: 1.3503x; 1.3503x over previous
//
#include <hip/hip_runtime.h>

// Problem constants (match reference setup_inputs()).
#define NV     10000     // base mesh vertices (N)
#define MPTS   500000    // target points (M)
#define BATCH  128       // scalar fields (B)

#define BLOCK  512       // threads per block (8 waves)
#define T      8         // m-values per thread -> 4096 m per block
#define BSPLIT 8         // grid.y: batch split -> 16 b-rows (8 pairs) per block
#define BPB    (BATCH / BSPLIT)   // 16 rows per block
#define MBLK   (BLOCK * T)        // 4096 m per block

// Two f-rows staged interleaved as float2 -> one ds_read_b64 feeds 2 outputs.
__global__ __launch_bounds__(BLOCK)
void bary_interp_kernel(const float* __restrict__ f,    // (B, N)
                        const int*   __restrict__ tri,  // (M, 3)
                        const float* __restrict__ w,    // (M, 3)
                        float*       __restrict__ out)  // (B, M)
{
    __shared__ float2 row2[NV];   // 80 KB: rows (b, b+1) interleaved

    const int tid    = (int)threadIdx.x;
    const int m_base = blockIdx.x * MBLK;
    const int b0     = blockIdx.y * BPB;

    // Load this thread's indices/weights once (reused across all BPB rows).
    int   i0[T], i1[T], i2[T];
    float w0[T], w1[T], w2[T];
#pragma unroll
    for (int t = 0; t < T; ++t) {
        const int m = m_base + t * BLOCK + tid;
        if (m < MPTS) {
            i0[t] = tri[3 * m + 0];
            i1[t] = tri[3 * m + 1];
            i2[t] = tri[3 * m + 2];
            w0[t] = w[3 * m + 0];
            w1[t] = w[3 * m + 1];
            w2[t] = w[3 * m + 2];
        } else {
            i0[t] = i1[t] = i2[t] = 0;
            w0[t] = w1[t] = w2[t] = 0.0f;
        }
    }

    for (int pp = 0; pp < BPB / 2; ++pp) {
        const int b = b0 + 2 * pp;

        if (pp) __syncthreads();   // everyone done reading row2 before overwrite

        // Stage rows b and b+1 interleaved: row2[n] = {f[b][n], f[b+1][n]}.
        // 4B/lane coalesced global loads; ds_write_b64 stride-8 (2-way = free).
        {
            const float* fa = f + (size_t)b * NV;
            const float* fb = fa + NV;
            for (int n = tid; n < NV; n += BLOCK)
                row2[n] = make_float2(fa[n], fb[n]);
        }
        __syncthreads();

        float* oa = out + (size_t)b * MPTS;
        float* ob = oa + MPTS;
#pragma unroll
        for (int t = 0; t < T; ++t) {
            const int m = m_base + t * BLOCK + tid;
            if (m < MPTS) {
                const float2 v0 = row2[i0[t]];
                const float2 v1 = row2[i1[t]];
                const float2 v2 = row2[i2[t]];
                oa[m] = v0.x * w0[t] + v1.x * w1[t] + v2.x * w2[t];
                ob[m] = v0.y * w0[t] + v1.y * w1[t] + v2.y * w2[t];
            }
        }
    }
}

extern "C" void kernel_launch(void* const* d_in, const int* in_sizes, int n_in,
                              void* d_out, int out_size, void* d_ws, size_t ws_size,
                              hipStream_t stream) {
    const float* f   = (const float*)d_in[0];   // (B, N)  float32
    const int*   tri = (const int*)  d_in[1];   // (M, 3)  int32
    const float* w   = (const float*)d_in[2];   // (M, 3)  float32
    float*       out = (float*)d_out;           // (B, M)  float32

    const int mblocks = (MPTS + MBLK - 1) / MBLK;  // 123
    dim3 grid(mblocks, BSPLIT);
    bary_interp_kernel<<<grid, BLOCK, 0, stream>>>(f, tri, w, out);
}

// Round 4
// 84.715 us; speedup vs baseline: 1.7618x; 1.3048x over previous
//
#include <hip/hip_runtime.h>

// Problem constants (match reference setup_inputs()).
#define NV     10000     // base mesh vertices (N)
#define MPTS   500000    // target points (M)
#define BATCH  128       // scalar fields (B)

#define BLOCK  1024      // threads per block (16 waves, 1 block/CU)
#define G      2         // float4-groups of m per thread -> 8 m/thread
#define MBLK   (BLOCK * 4 * G)    // 8192 m per block
#define BPB    8                  // rows per block
#define BSPLIT (BATCH / BPB)      // 16
#define PAIRS  (BPB / 2)          // 4 double-buffered pair-phases

typedef float v4f __attribute__((ext_vector_type(4)));  // native clang vector
typedef int   v4i __attribute__((ext_vector_type(4)));

// Two f-rows interleaved as float2 in LDS; double-buffered (2 x 80,000 B).
__global__ __launch_bounds__(BLOCK, 4)
void bary_interp_kernel(const float* __restrict__ f,    // (B, N)
                        const int*   __restrict__ tri,  // (M, 3)
                        const float* __restrict__ w,    // (M, 3)
                        float*       __restrict__ out)  // (B, M)
{
    __shared__ v4f buf4[2][NV / 2];   // viewed as float2 row2[NV]

    const int tid    = (int)threadIdx.x;
    const int m_base = blockIdx.x * MBLK;
    const int b0     = blockIdx.y * BPB;

    // ---- Load this thread's indices/weights once (vectorized int4/float4).
    // Group g covers 4 consecutive m at m_base + g*(BLOCK*4) + tid*4.
    int   idx[G][12];
    float wt [G][12];
    bool  valid[G];
#pragma unroll
    for (int g = 0; g < G; ++g) {
        const int m = m_base + g * (BLOCK * 4) + tid * 4;
        valid[g] = (m < MPTS);           // M % 4 == 0, m % 4 == 0
        if (valid[g]) {
            const v4i* ti = reinterpret_cast<const v4i*>(tri + 3 * (size_t)m);
            const v4f* wi = reinterpret_cast<const v4f*>(w + 3 * (size_t)m);
#pragma unroll
            for (int q = 0; q < 3; ++q) {
                const v4i a  = ti[q];
                const v4f bv = wi[q];
#pragma unroll
                for (int e = 0; e < 4; ++e) {
                    idx[g][4*q+e] = a[e];
                    wt [g][4*q+e] = bv[e];
                }
            }
        } else {
#pragma unroll
            for (int q = 0; q < 12; ++q) { idx[g][q] = 0; wt[g][q] = 0.0f; }
        }
    }

    // ---- Stage rows (b, b+1) interleaved: row2[n] = {f[b][n], f[b+1][n]}.
    auto stage = [&](v4f* dst, int b) {
        const v4f* fa = reinterpret_cast<const v4f*>(f + (size_t)b * NV);
        const v4f* fb = reinterpret_cast<const v4f*>(f + (size_t)(b + 1) * NV);
        for (int i = tid; i < NV / 4; i += BLOCK) {
            const v4f a = fa[i];
            const v4f c = fb[i];
            v4f lo = { a.x, c.x, a.y, c.y };
            v4f hi = { a.z, c.z, a.w, c.w };
            dst[2*i+0] = lo;
            dst[2*i+1] = hi;
        }
    };

    stage(buf4[0], b0);
    __syncthreads();

    for (int p = 0; p < PAIRS; ++p) {
        // Issue next pair's staging FIRST so its latency hides under compute.
        if (p + 1 < PAIRS) stage(buf4[(p + 1) & 1], b0 + 2 * (p + 1));

        const float2* row2 = reinterpret_cast<const float2*>(buf4[p & 1]);
        const int b  = b0 + 2 * p;
        float* oa = out + (size_t)b * MPTS;
        float* ob = oa + MPTS;

#pragma unroll
        for (int g = 0; g < G; ++g) {
            if (valid[g]) {
                const int m = m_base + g * (BLOCK * 4) + tid * 4;
                v4f ra, rc;
#pragma unroll
                for (int e = 0; e < 4; ++e) {
                    const float2 v0 = row2[idx[g][3*e+0]];
                    const float2 v1 = row2[idx[g][3*e+1]];
                    const float2 v2 = row2[idx[g][3*e+2]];
                    ra[e] = v0.x*wt[g][3*e+0] + v1.x*wt[g][3*e+1] + v2.x*wt[g][3*e+2];
                    rc[e] = v0.y*wt[g][3*e+0] + v1.y*wt[g][3*e+1] + v2.y*wt[g][3*e+2];
                }
                __builtin_nontemporal_store(ra, reinterpret_cast<v4f*>(oa + m));
                __builtin_nontemporal_store(rc, reinterpret_cast<v4f*>(ob + m));
            }
        }
        __syncthreads();   // next buffer staged; current buffer free for reuse
    }
}

extern "C" void kernel_launch(void* const* d_in, const int* in_sizes, int n_in,
                              void* d_out, int out_size, void* d_ws, size_t ws_size,
                              hipStream_t stream) {
    const float* f   = (const float*)d_in[0];   // (B, N)  float32
    const int*   tri = (const int*)  d_in[1];   // (M, 3)  int32
    const float* w   = (const float*)d_in[2];   // (M, 3)  float32
    float*       out = (float*)d_out;           // (B, M)  float32

    const int mblocks = (MPTS + MBLK - 1) / MBLK;  // 62
    dim3 grid(mblocks, BSPLIT);
    bary_interp_kernel<<<grid, BLOCK, 0, stream>>>(f, tri, w, out);
}

// Round 5
// 60.431 us; speedup vs baseline: 2.4698x; 1.4018x over previous
//
#include <hip/hip_runtime.h>

// Problem constants (match reference setup_inputs()).
#define NV     10000     // base mesh vertices (N)
#define MPTS   500000    // target points (M)
#define BATCH  128       // scalar fields (B)

#define BLOCK  1024      // threads per block (16 waves, 1 block/CU)
#define G      2         // float4-groups of m per thread -> 8 m/thread
#define MBLK   (BLOCK * 4 * G)    // 8192 m per block
#define BPB    32                 // rows per block
#define BSPLIT (BATCH / BPB)      // 4  -> grid 62x4 = 248 blocks (1 round)
#define PAIRS  (BPB / 2)          // 16 double-buffered pair-phases

typedef float v4f __attribute__((ext_vector_type(4)));  // native clang vector
typedef int   v4i __attribute__((ext_vector_type(4)));

// Barrier that waits only for LDS ops (lgkmcnt) — NOT vmcnt. Our nontemporal
// stores may stay in flight across phases (nobody reads them); stage() global
// loads are consumed by ds_writes whose data-dep waits the compiler inserts.
// This keeps the store pipe draining WHILE other phases gather from LDS.
__device__ inline void lds_barrier() {
    asm volatile("s_waitcnt lgkmcnt(0)" ::: "memory");
    __builtin_amdgcn_sched_barrier(0);
    __builtin_amdgcn_s_barrier();
}

// Two f-rows interleaved as float2 in LDS; double-buffered (2 x 80,000 B).
__global__ __launch_bounds__(BLOCK, 4)
void bary_interp_kernel(const float* __restrict__ f,    // (B, N)
                        const int*   __restrict__ tri,  // (M, 3)
                        const float* __restrict__ w,    // (M, 3)
                        float*       __restrict__ out)  // (B, M)
{
    __shared__ v4f buf4[2][NV / 2];   // viewed as float2 row2[NV]

    const int tid    = (int)threadIdx.x;
    const int m_base = blockIdx.x * MBLK;
    const int b0     = blockIdx.y * BPB;

    // ---- Load this thread's indices/weights once (vectorized int4/float4).
    // Group g covers 4 consecutive m at m_base + g*(BLOCK*4) + tid*4.
    int   idx[G][12];
    float wt [G][12];
    bool  valid[G];
#pragma unroll
    for (int g = 0; g < G; ++g) {
        const int m = m_base + g * (BLOCK * 4) + tid * 4;
        valid[g] = (m < MPTS);           // M % 4 == 0, m % 4 == 0
        if (valid[g]) {
            const v4i* ti = reinterpret_cast<const v4i*>(tri + 3 * (size_t)m);
            const v4f* wi = reinterpret_cast<const v4f*>(w + 3 * (size_t)m);
#pragma unroll
            for (int q = 0; q < 3; ++q) {
                const v4i a  = ti[q];
                const v4f bv = wi[q];
#pragma unroll
                for (int e = 0; e < 4; ++e) {
                    idx[g][4*q+e] = a[e];
                    wt [g][4*q+e] = bv[e];
                }
            }
        } else {
#pragma unroll
            for (int q = 0; q < 12; ++q) { idx[g][q] = 0; wt[g][q] = 0.0f; }
        }
    }

    // ---- Stage rows (b, b+1) interleaved: row2[n] = {f[b][n], f[b+1][n]}.
    auto stage = [&](v4f* dst, int b) {
        const v4f* fa = reinterpret_cast<const v4f*>(f + (size_t)b * NV);
        const v4f* fb = reinterpret_cast<const v4f*>(f + (size_t)(b + 1) * NV);
        for (int i = tid; i < NV / 4; i += BLOCK) {
            const v4f a = fa[i];
            const v4f c = fb[i];
            v4f lo = { a.x, c.x, a.y, c.y };
            v4f hi = { a.z, c.z, a.w, c.w };
            dst[2*i+0] = lo;
            dst[2*i+1] = hi;
        }
    };

    stage(buf4[0], b0);
    lds_barrier();

    for (int p = 0; p < PAIRS; ++p) {
        // Issue next pair's staging FIRST so its latency hides under compute.
        if (p + 1 < PAIRS) stage(buf4[(p + 1) & 1], b0 + 2 * (p + 1));

        const float2* row2 = reinterpret_cast<const float2*>(buf4[p & 1]);
        const int b  = b0 + 2 * p;
        float* oa = out + (size_t)b * MPTS;
        float* ob = oa + MPTS;

#pragma unroll
        for (int g = 0; g < G; ++g) {
            if (valid[g]) {
                const int m = m_base + g * (BLOCK * 4) + tid * 4;
                v4f ra, rc;
#pragma unroll
                for (int e = 0; e < 4; ++e) {
                    const float2 v0 = row2[idx[g][3*e+0]];
                    const float2 v1 = row2[idx[g][3*e+1]];
                    const float2 v2 = row2[idx[g][3*e+2]];
                    ra[e] = v0.x*wt[g][3*e+0] + v1.x*wt[g][3*e+1] + v2.x*wt[g][3*e+2];
                    rc[e] = v0.y*wt[g][3*e+0] + v1.y*wt[g][3*e+1] + v2.y*wt[g][3*e+2];
                }
                __builtin_nontemporal_store(ra, reinterpret_cast<v4f*>(oa + m));
                __builtin_nontemporal_store(rc, reinterpret_cast<v4f*>(ob + m));
            }
        }
        // LDS-only barrier: stores remain in flight; buf[(p+1)&1] is now fully
        // staged (lgkmcnt covers the ds_writes) and buf[p&1] is free.
        lds_barrier();
    }
}

extern "C" void kernel_launch(void* const* d_in, const int* in_sizes, int n_in,
                              void* d_out, int out_size, void* d_ws, size_t ws_size,
                              hipStream_t stream) {
    const float* f   = (const float*)d_in[0];   // (B, N)  float32
    const int*   tri = (const int*)  d_in[1];   // (M, 3)  int32
    const float* w   = (const float*)d_in[2];   // (M, 3)  float32
    float*       out = (float*)d_out;           // (B, M)  float32

    const int mblocks = (MPTS + MBLK - 1) / MBLK;  // 62
    dim3 grid(mblocks, BSPLIT);
    bary_interp_kernel<<<grid, BLOCK, 0, stream>>>(f, tri, w, out);
}

// Round 6
// 58.324 us; speedup vs baseline: 2.5590x; 1.0361x over previous
//
#include <hip/hip_runtime.h>

// Problem constants (match reference setup_inputs()).
#define NV     10000     // base mesh vertices (N)
#define MPTS   500000    // target points (M)
#define BATCH  128       // scalar fields (B)

#define BLOCK  1024      // threads per block (16 waves, 1 block/CU)
#define G      2         // float4-groups of m per thread -> 8 m/thread
#define MBLK   (BLOCK * 4 * G)    // 8192 m per block
#define BPB    32                 // rows per block
#define BSPLIT (BATCH / BPB)      // 4 batch-split blocks per m-slice
#define PAIRS  (BPB / 2)          // 16 double-buffered pair-phases
#define NGROUPS ((MPTS + MBLK - 1) / MBLK)   // 62 m-slices
#define GRID   256                // 8 XCD slots x 32 (8 pad blocks exit)

typedef float v4f __attribute__((ext_vector_type(4)));  // native clang vector
typedef int   v4i __attribute__((ext_vector_type(4)));

// Barrier that waits only for LDS ops (lgkmcnt) — NOT vmcnt. Our nontemporal
// stores may stay in flight across phases (nobody reads them); stage() global
// loads are consumed by ds_writes whose data-dep waits the compiler inserts.
__device__ inline void lds_barrier() {
    asm volatile("s_waitcnt lgkmcnt(0)" ::: "memory");
    __builtin_amdgcn_sched_barrier(0);
    __builtin_amdgcn_s_barrier();
}

// Two f-rows interleaved as float2 in LDS; double-buffered (2 x 80,000 B).
__global__ __launch_bounds__(BLOCK, 4)
void bary_interp_kernel(const float* __restrict__ f,    // (B, N)
                        const int*   __restrict__ tri,  // (M, 3)
                        const float* __restrict__ w,    // (M, 3)
                        float*       __restrict__ out)  // (B, M)
{
    __shared__ v4f buf4[2][NV / 2];   // viewed as float2 row2[NV]

    // XCD-grouped bijective mapping: dispatcher assigns XCD = blockIdx % 8
    // (m09). Put the BSPLIT=4 blocks sharing one m-slice (same tri/w bytes)
    // on the SAME XCD so its L2 serves the re-reads, instead of 4 HBM trips
    // racing the 256 MB store stream.
    const int bid = (int)blockIdx.x;
    const int xcd = bid & 7;
    const int seq = bid >> 3;               // 0..31 within this XCD
    const int g   = xcd * 8 + (seq >> 2);   // m-slice 0..63
    const int y   = seq & 3;                // batch-split 0..3
    if (g >= NGROUPS) return;               // 8 pad blocks exit

    const int tid    = (int)threadIdx.x;
    const int m_base = g * MBLK;
    const int b0     = y * BPB;

    // ---- Load this thread's indices/weights once (vectorized int4/float4).
    int   idx[G][12];
    float wt [G][12];
    bool  valid[G];
#pragma unroll
    for (int gg = 0; gg < G; ++gg) {
        const int m = m_base + gg * (BLOCK * 4) + tid * 4;
        valid[gg] = (m < MPTS);           // M % 4 == 0, m % 4 == 0
        if (valid[gg]) {
            const v4i* ti = reinterpret_cast<const v4i*>(tri + 3 * (size_t)m);
            const v4f* wi = reinterpret_cast<const v4f*>(w + 3 * (size_t)m);
#pragma unroll
            for (int q = 0; q < 3; ++q) {
                const v4i a  = ti[q];
                const v4f bv = wi[q];
#pragma unroll
                for (int e = 0; e < 4; ++e) {
                    idx[gg][4*q+e] = a[e];
                    wt [gg][4*q+e] = bv[e];
                }
            }
        } else {
#pragma unroll
            for (int q = 0; q < 12; ++q) { idx[gg][q] = 0; wt[gg][q] = 0.0f; }
        }
    }

    // ---- Stage rows (b, b+1) interleaved: row2[n] = {f[b][n], f[b+1][n]}.
    auto stage = [&](v4f* dst, int b) {
        const v4f* fa = reinterpret_cast<const v4f*>(f + (size_t)b * NV);
        const v4f* fb = reinterpret_cast<const v4f*>(f + (size_t)(b + 1) * NV);
        for (int i = tid; i < NV / 4; i += BLOCK) {
            const v4f a = fa[i];
            const v4f c = fb[i];
            v4f lo = { a.x, c.x, a.y, c.y };
            v4f hi = { a.z, c.z, a.w, c.w };
            dst[2*i+0] = lo;
            dst[2*i+1] = hi;
        }
    };

    stage(buf4[0], b0);
    lds_barrier();

    for (int p = 0; p < PAIRS; ++p) {
        // Issue next pair's staging FIRST so its latency hides under compute.
        if (p + 1 < PAIRS) stage(buf4[(p + 1) & 1], b0 + 2 * (p + 1));

        const float2* row2 = reinterpret_cast<const float2*>(buf4[p & 1]);
        const int b  = b0 + 2 * p;
        float* oa = out + (size_t)b * MPTS;
        float* ob = oa + MPTS;

#pragma unroll
        for (int gg = 0; gg < G; ++gg) {
            if (valid[gg]) {
                const int m = m_base + gg * (BLOCK * 4) + tid * 4;
                v4f ra, rc;
#pragma unroll
                for (int e = 0; e < 4; ++e) {
                    const float2 v0 = row2[idx[gg][3*e+0]];
                    const float2 v1 = row2[idx[gg][3*e+1]];
                    const float2 v2 = row2[idx[gg][3*e+2]];
                    ra[e] = v0.x*wt[gg][3*e+0] + v1.x*wt[gg][3*e+1] + v2.x*wt[gg][3*e+2];
                    rc[e] = v0.y*wt[gg][3*e+0] + v1.y*wt[gg][3*e+1] + v2.y*wt[gg][3*e+2];
                }
                __builtin_nontemporal_store(ra, reinterpret_cast<v4f*>(oa + m));
                __builtin_nontemporal_store(rc, reinterpret_cast<v4f*>(ob + m));
            }
        }
        // LDS-only barrier: stores remain in flight; buf[(p+1)&1] is staged.
        lds_barrier();
    }
}

extern "C" void kernel_launch(void* const* d_in, const int* in_sizes, int n_in,
                              void* d_out, int out_size, void* d_ws, size_t ws_size,
                              hipStream_t stream) {
    const float* f   = (const float*)d_in[0];   // (B, N)  float32
    const int*   tri = (const int*)  d_in[1];   // (M, 3)  int32
    const float* w   = (const float*)d_in[2];   // (M, 3)  float32
    float*       out = (float*)d_out;           // (B, M)  float32

    bary_interp_kernel<<<dim3(GRID), BLOCK, 0, stream>>>(f, tri, w, out);
}